// Round 4
// baseline (214.649 us; speedup 1.0000x reference)
//
#include <hip/hip_runtime.h>
#include <stdint.h>

typedef unsigned short u16;
typedef __bf16 bf16x8 __attribute__((ext_vector_type(8)));
typedef short  short8 __attribute__((ext_vector_type(8)));
typedef float  f32x4  __attribute__((ext_vector_type(4)));
typedef float  float4v __attribute__((ext_vector_type(4)));
typedef uint32_t u32x2 __attribute__((ext_vector_type(2)));

#define NG    32
#define NPG   512
#define HIDD  512
#define NH    8
#define HD    64
#define NE    262144
#define NNODE (NG*NPG)

__device__ __forceinline__ float fexp2(float x) { return __builtin_amdgcn_exp2f(x); }

__device__ __forceinline__ u16 f2bf(float f) {
  union { float f; uint32_t u; } x; x.f = f;
  uint32_t r = x.u + 0x7FFFu + ((x.u >> 16) & 1u);
  return (u16)(r >> 16);
}
__device__ __forceinline__ float bf2f(u16 b) {
  union { uint32_t u; float f; } x; x.u = ((uint32_t)b) << 16;
  return x.f;
}
__device__ __forceinline__ bf16x8 ldfrag(const u16* p) {
  short8 t = *(const short8*)p;
  return __builtin_bit_cast(bf16x8, t);
}
__device__ __forceinline__ f32x4 mfma16(bf16x8 a, bf16x8 b, f32x4 c) {
  return __builtin_amdgcn_mfma_f32_16x16x32_bf16(a, b, c, 0, 0, 0);
}
__device__ __forceinline__ void gl2lds16(const void* g, void* l) {
  __builtin_amdgcn_global_load_lds((const __attribute__((address_space(1))) void*)g,
                                   (__attribute__((address_space(3))) void*)l, 16, 0, 0);
}
__device__ __forceinline__ void st(u16* p, float v)   { *p = f2bf(v); }
__device__ __forceinline__ void st(float* p, float v) { *p = v; }

// ---------------- prep kernels ----------------

__global__ void k_cast_x(const float* __restrict__ x, u16* __restrict__ xb) {
  size_t i = ((size_t)blockIdx.x * 256 + threadIdx.x) * 8;
  float4v v0 = *(const float4v*)(x + i);
  float4v v1 = *(const float4v*)(x + i + 4);
  short8 r;
  r[0]=(short)f2bf(v0[0]); r[1]=(short)f2bf(v0[1]); r[2]=(short)f2bf(v0[2]); r[3]=(short)f2bf(v0[3]);
  r[4]=(short)f2bf(v1[0]); r[5]=(short)f2bf(v1[1]); r[6]=(short)f2bf(v1[2]); r[7]=(short)f2bf(v1[3]);
  *(short8*)(xb + i) = r;
}

// wt[z][n][k] = W_z[k][n]
__global__ void k_transw(const float* __restrict__ W0, const float* __restrict__ W1,
                         const float* __restrict__ W2, const float* __restrict__ W3,
                         u16* __restrict__ wt) {
  const float* W = blockIdx.z==0 ? W0 : blockIdx.z==1 ? W1 : blockIdx.z==2 ? W2 : W3;
  u16* out = wt + (size_t)blockIdx.z * HIDD * HIDD;
  __shared__ float tl[32][33];
  int tx = threadIdx.x, ty = threadIdx.y;
  int x0 = blockIdx.x * 32, y0 = blockIdx.y * 32;
  #pragma unroll
  for (int i = 0; i < 4; ++i) tl[ty + i*8][tx] = W[(size_t)(y0 + ty + i*8) * HIDD + x0 + tx];
  __syncthreads();
  #pragma unroll
  for (int i = 0; i < 4; ++i) out[(size_t)(x0 + ty + i*8) * HIDD + (y0 + tx)] = f2bf(tl[tx][ty + i*8]);
}

__global__ void k_count(const int* __restrict__ ei, int* __restrict__ counts) {
  int e = blockIdx.x * 256 + threadIdx.x;
  atomicAdd(&counts[ei[e]], 1);
}

__global__ void k_scan(const int* __restrict__ counts, int* __restrict__ rowstart) {
  __shared__ int arr[1024];
  int t = threadIdx.x;
  int c[16]; int s = 0;
  #pragma unroll
  for (int i = 0; i < 16; ++i) { c[i] = counts[t*16 + i]; s += c[i]; }
  arr[t] = s;
  __syncthreads();
  for (int off = 1; off < 1024; off <<= 1) {
    int v = (t >= off) ? arr[t - off] : 0;
    __syncthreads();
    arr[t] += v;
    __syncthreads();
  }
  int start = arr[t] - s;
  #pragma unroll
  for (int i = 0; i < 16; ++i) { rowstart[t*16 + i] = start; start += c[i]; }
  if (t == 1023) rowstart[16384] = start;
}

// packed[(rowstart[src]+pos)*8 + h] = dst | f16(exp(edge_attr@We+be))<<16
__global__ void k_fill(const int* __restrict__ ei, const float* __restrict__ ea,
                       const float* __restrict__ We, const float* __restrict__ be,
                       const int* __restrict__ rowstart, int* __restrict__ cursor,
                       uint32_t* __restrict__ packed) {
  __shared__ float w[128];
  __shared__ float bb[8];
  int t = threadIdx.x;
  if (t < 128) w[t] = We[t];
  if (t < 8)   bb[t] = be[t];
  __syncthreads();
  int e = blockIdx.x * 256 + t;
  int src = ei[e];
  int dst = ei[NE + e];
  const float* ap = ea + (size_t)e * 16;
  float a[16];
  #pragma unroll
  for (int i = 0; i < 16; i += 4) {
    float4v v = *(const float4v*)(ap + i);
    a[i]=v[0]; a[i+1]=v[1]; a[i+2]=v[2]; a[i+3]=v[3];
  }
  float acc[8];
  #pragma unroll
  for (int hh = 0; hh < 8; ++hh) acc[hh] = bb[hh];
  #pragma unroll
  for (int d = 0; d < 16; ++d)
    #pragma unroll
    for (int hh = 0; hh < 8; ++hh) acc[hh] += a[d] * w[d*8 + hh];
  int pos = atomicAdd(&cursor[src], 1);
  size_t base = ((size_t)(rowstart[src] + pos)) * 8;
  #pragma unroll
  for (int hh = 0; hh < 8; ++hh) {
    float m = fexp2(acc[hh] * 1.44269504089f);
    union { _Float16 hf; u16 us; } cv; cv.hf = (_Float16)m;
    packed[base + hh] = (uint32_t)(dst & (NPG - 1)) | ((uint32_t)cv.us << 16);
  }
}

// ---------------- GEMM (128x128, BK=32, 3-buffer, 1 barrier/iter) ----------------
// VOUT: z==2 path writes V^T tiles (64d x 32keys, slot-permuted) via LDS assembly.

template <typename OT, bool VOUT>
__device__ void gemm_body(const u16* __restrict__ A, const u16* __restrict__ Bt,
                          const float* __restrict__ bias, OT* __restrict__ C,
                          u16* __restrict__ vtg) {
  __shared__ u16 smem[24576];  // 48KB: 3 bufs x (8KB A + 8KB B)
  const int tid = threadIdx.x;
  const int w = tid >> 6, l = tid & 63, lr = l & 15, lg = l >> 4;
  // XCD-aware swizzle within the 512-block z-slice (512 % 8 == 0)
  const int idl = blockIdx.x + (blockIdx.y << 2);
  const int nid = (idl & 7) * 64 + (idl >> 3);
  const int bn0 = (nid & 3) * 128, bm0 = (nid >> 2) * 128;
  const int wr = w >> 1, wc = w & 1;
  f32x4 acc[4][4];
  #pragma unroll
  for (int i = 0; i < 4; ++i)
    #pragma unroll
    for (int j = 0; j < 4; ++j) acc[i][j] = (f32x4){0.f, 0.f, 0.f, 0.f};

  const int o1 = w * 1024 + l * 16;
  auto stageAB = [&](int kt, int buf) {
    #pragma unroll
    for (int rnd = 0; rnd < 2; ++rnd) {
      const int o = rnd * 4096 + o1;
      const int row = o >> 6, colb = o & 63;
      gl2lds16((const char*)A  + ((size_t)(bm0 + row) * HIDD + kt * 32) * 2 + colb,
               (char*)smem + buf * 16384 + o);
      gl2lds16((const char*)Bt + ((size_t)(bn0 + row) * HIDD + kt * 32) * 2 + colb,
               (char*)smem + buf * 16384 + 8192 + o);
    }
  };

  stageAB(0, 0); stageAB(1, 1);
  for (int kt = 0; kt < 16; ++kt) {
    if (kt < 15) asm volatile("s_waitcnt vmcnt(4)" ::: "memory");
    else         asm volatile("s_waitcnt vmcnt(0)" ::: "memory");
    __syncthreads();
    if (kt < 14) stageAB(kt + 2, (kt + 2) % 3);
    const u16* Ab = smem + (kt % 3) * 8192;
    const u16* Bb = Ab + 4096;
    bf16x8 af[4], bfr[4];
    #pragma unroll
    for (int i = 0; i < 4; ++i) af[i]  = ldfrag(&Ab[(wr*64 + i*16 + lr) * 32 + lg*8]);
    #pragma unroll
    for (int j = 0; j < 4; ++j) bfr[j] = ldfrag(&Bb[(wc*64 + j*16 + lr) * 32 + lg*8]);
    #pragma unroll
    for (int i = 0; i < 4; ++i)
      #pragma unroll
      for (int j = 0; j < 4; ++j)
        acc[i][j] = mfma16(af[i], bfr[j], acc[i][j]);
  }

  if constexpr (VOUT) {
    // assemble V^T tiles in LDS: tile8 = h_loc*4 + kt_loc; [64 d][4 slots][8 jj]
    __syncthreads();
    #pragma unroll
    for (int j = 0; j < 4; ++j) {
      const int d = j * 16 + lr;
      const float bv = bias[bn0 + wc*64 + j*16 + lr];
      #pragma unroll
      for (int i = 0; i < 4; ++i) {
        const int tile8 = wc * 4 + wr * 2 + (i >> 1);
        const int jb = (i & 1) * 2 + (lg >> 1);
        const int slot = (jb + (d >> 1)) & 3;
        const int lidx = tile8 * 2048 + d * 32 + slot * 8 + (lg & 1) * 4;
        uint32_t lo = (uint32_t)f2bf(acc[i][j][0] + bv) | ((uint32_t)f2bf(acc[i][j][1] + bv) << 16);
        uint32_t hi = (uint32_t)f2bf(acc[i][j][2] + bv) | ((uint32_t)f2bf(acc[i][j][3] + bv) << 16);
        *(u32x2*)&smem[lidx] = (u32x2){lo, hi};
      }
    }
    __syncthreads();
    const int b = bm0 >> 9, kt0 = (bm0 >> 5) & 15, h0 = bn0 >> 6;
    #pragma unroll
    for (int t8 = 0; t8 < 8; ++t8) {
      const int h = h0 + (t8 >> 2), ktg = kt0 + (t8 & 3);
      size_t base = ((size_t)(b * 8 + h)) * 32768 + (size_t)ktg * 2048;
      *(short8*)(vtg + base + tid * 8) = *(const short8*)&smem[t8 * 2048 + tid * 8];
    }
  } else {
    #pragma unroll
    for (int j = 0; j < 4; ++j) {
      const int col = bn0 + wc*64 + j*16 + lr;
      const float bv = bias[col];
      #pragma unroll
      for (int i = 0; i < 4; ++i) {
        const int row0 = bm0 + wr*64 + i*16 + lg*4;
        #pragma unroll
        for (int q = 0; q < 4; ++q)
          st(&C[(size_t)(row0 + q) * HIDD + col], acc[i][j][q] + bv);
      }
    }
  }
}

__global__ __launch_bounds__(256, 3) void k_gemm_qkv(
    const u16* __restrict__ A, const u16* __restrict__ Wt,
    const float* __restrict__ b0, const float* __restrict__ b1, const float* __restrict__ b2,
    u16* __restrict__ O0, u16* __restrict__ O1, u16* __restrict__ vtg) {
  int z = blockIdx.z;
  const u16* Bt = Wt + (size_t)z * HIDD * HIDD;
  if (z == 0)      gemm_body<u16, false>(A, Bt, b0, O0, nullptr);
  else if (z == 1) gemm_body<u16, false>(A, Bt, b1, O1, nullptr);
  else             gemm_body<u16, true >(A, Bt, b2, nullptr, vtg);
}

__global__ __launch_bounds__(256, 3) void k_gemm_out(
    const u16* __restrict__ A, const u16* __restrict__ Bt,
    const float* __restrict__ bias, float* __restrict__ C) {
  gemm_body<float, false>(A, Bt, bias, C, nullptr);
}

// ---------------- fused attention ----------------
// Swapped QK^T (mfma(K,Q)): lane owns q-row lr, keys t*16+lg*4+q -> packed b64 P-writes.
// V^T pre-transposed globally; staged via gl2lds, 3-buffer, counted vmcnt.

__global__ __launch_bounds__(256, 2) void k_attn(
    const u16* __restrict__ qb, const u16* __restrict__ kb, const u16* __restrict__ vtg,
    const uint32_t* __restrict__ packed, const int* __restrict__ rowstart,
    u16* __restrict__ ab) {
  __shared__ u16 pl[64 * 512];   // 64KB P; first 24KB doubles as K staging (3 x 8KB)
  __shared__ u16 vbuf[3 * 2048]; // 12KB: 3 x 4KB V^T tiles
  __shared__ float red[64];
  const int tid = threadIdx.x, w = tid >> 6, l = tid & 63, lr = l & 15, lg = l >> 4;

  const int id = blockIdx.x;
  const int nid = (id & 7) * 256 + (id >> 3);   // XCD-contiguous (2048 % 8 == 0)
  const int q0 = (nid & 7) * 64;
  const int h  = (nid >> 3) & 7;
  const int b  = nid >> 6;
  const int bh = b * 8 + h;

  bf16x8 qf[2];
  {
    int node = b * NPG + q0 + w * 16 + lr;
    const u16* qp = qb + (size_t)node * HIDD + h * HD + lg * 8;
    qf[0] = ldfrag(qp);
    qf[1] = ldfrag(qp + 32);
  }

  auto stageK = [&](int kt, int buf) {
    #pragma unroll
    for (int rnd = 0; rnd < 2; ++rnd) {
      int o = rnd * 4096 + w * 1024 + l * 16;
      int key = o >> 7, db = o & 127;
      int col = db ^ ((key & 7) << 4);
      gl2lds16((const char*)kb + ((size_t)(b * NPG + kt * 64 + key) * HIDD + h * HD) * 2 + col,
               (char*)pl + buf * 8192 + o);
    }
  };
  auto stageV = [&](int vt, int buf) {
    gl2lds16((const char*)vtg + ((size_t)bh * 32768 + (size_t)vt * 2048) * 2 + tid * 16,
             (char*)vbuf + buf * 4096 + tid * 16);
  };

  // ---- S^T = K Q^T (swapped): lane (lr,lg) holds S[key=t*16+lg*4+q][qrow=lr] ----
  f32x4 sacc[32];
  #pragma unroll
  for (int t = 0; t < 32; ++t) sacc[t] = (f32x4){0.f, 0.f, 0.f, 0.f};

  stageK(0, 0); stageK(1, 1);
  #pragma unroll
  for (int kt = 0; kt < 8; ++kt) {
    if (kt < 7) asm volatile("s_waitcnt vmcnt(2)" ::: "memory");
    else        asm volatile("s_waitcnt vmcnt(0)" ::: "memory");
    __syncthreads();
    if (kt < 6) stageK(kt + 2, (kt + 2) % 3);
    const u16* kB = pl + (kt % 3) * 4096;
    #pragma unroll
    for (int ct = 0; ct < 4; ++ct) {
      int key = ct * 16 + lr;
      #pragma unroll
      for (int ks = 0; ks < 2; ++ks) {
        int db = ((ks * 32 + lg * 8) * 2) ^ ((key & 7) << 4);
        bf16x8 kf = ldfrag(&kB[(key * 128 + db) >> 1]);
        sacc[kt * 4 + ct] = mfma16(kf, qf[ks], sacc[kt * 4 + ct]);  // swapped
      }
    }
  }

  // V tiles 0,1 fly under softmax
  stageV(0, 0); stageV(1, 1);
  __syncthreads();  // all K-buf reads done before P overwrites pl

  // ---- softmax (row = lr), packed b64 P-writes, reg row-sum ----
  float m = -1e30f;
  #pragma unroll
  for (int t = 0; t < 32; ++t) {
    #pragma unroll
    for (int q = 0; q < 4; ++q) m = fmaxf(m, sacc[t][q]);
  }
  m = fmaxf(m, __shfl_xor(m, 16, 64));
  m = fmaxf(m, __shfl_xor(m, 32, 64));
  const float c1 = 0.125f * 1.44269504089f;   // scale * log2e
  const float mx2 = m * c1;
  const int prow = w * 16 + lr;
  const int swz = ((prow ^ (prow >> 3)) & 7) << 4;
  float rs = 0.f;
  #pragma unroll
  for (int t = 0; t < 32; ++t) {
    float p0 = fexp2(__builtin_fmaf(sacc[t][0], c1, -mx2));
    float p1 = fexp2(__builtin_fmaf(sacc[t][1], c1, -mx2));
    float p2 = fexp2(__builtin_fmaf(sacc[t][2], c1, -mx2));
    float p3 = fexp2(__builtin_fmaf(sacc[t][3], c1, -mx2));
    rs += (p0 + p1) + (p2 + p3);
    uint32_t lo = (uint32_t)f2bf(p0) | ((uint32_t)f2bf(p1) << 16);
    uint32_t hi = (uint32_t)f2bf(p2) | ((uint32_t)f2bf(p3) << 16);
    int byteo = prow * 1024 + ((t * 32 + lg * 8) ^ swz);
    *(u32x2*)((char*)pl + byteo) = (u32x2){lo, hi};
  }
  rs += __shfl_xor(rs, 16, 64);
  rs += __shfl_xor(rs, 32, 64);
  if (l < 16) red[w * 16 + l] = rs;
  __syncthreads();

  // ---- edge multipliers: 4 threads/row, disjoint dst&3 classes ----
  {
    int r = tid >> 2, c = tid & 3;
    int grow = b * NPG + q0 + r;
    int s0 = rowstart[grow], s1 = rowstart[grow + 1];
    int swzp = ((r ^ (r >> 3)) & 7) << 4;
    float delta = 0.f;
    for (int s = s0; s < s1; ++s) {
      uint32_t u = packed[(size_t)s * 8 + h];
      int dst = (int)(u & 0xFFFFu);
      if ((dst & 3) == c) {
        union { u16 us; _Float16 hf; } cv; cv.us = (u16)(u >> 16);
        float mult = (float)cv.hf;
        int idx = (r * 1024 + ((dst * 2) ^ swzp)) >> 1;
        float old = bf2f(pl[idx]);
        u16 nb = f2bf(old * mult);
        pl[idx] = nb;
        delta += bf2f(nb) - old;
      }
    }
    atomicAdd(&red[r], delta);
  }
  __syncthreads();
  if (tid < 64) red[tid] = 1.0f / red[tid];

  // ---- O = P V : 16 tiles of 32 keys, async 3-buffer staging ----
  f32x4 oacc[4];
  #pragma unroll
  for (int dt = 0; dt < 4; ++dt) oacc[dt] = (f32x4){0.f, 0.f, 0.f, 0.f};

  #pragma unroll
  for (int vt = 0; vt < 16; ++vt) {
    if (vt < 15) asm volatile("s_waitcnt vmcnt(1)" ::: "memory");
    else         asm volatile("s_waitcnt vmcnt(0)" ::: "memory");
    __syncthreads();
    if (vt < 14) stageV(vt + 2, (vt + 2) % 3);
    const u16* vB = vbuf + (vt % 3) * 2048;
    int pcolb = (vt * 64 + lg * 16) ^ swz;
    bf16x8 pa = ldfrag(&pl[(prow * 1024 + pcolb) >> 1]);
    #pragma unroll
    for (int dt = 0; dt < 4; ++dt) {
      int d = dt * 16 + lr;
      bf16x8 vf = ldfrag(&vB[d * 32 + ((lg + (d >> 1)) & 3) * 8]);
      oacc[dt] = mfma16(pa, vf, oacc[dt]);
    }
  }

  // ---- normalize + store bf16 ----
  #pragma unroll
  for (int dt = 0; dt < 4; ++dt) {
    #pragma unroll
    for (int q = 0; q < 4; ++q) {
      int row = w * 16 + lg * 4 + q;
      float v = oacc[dt][q] * red[row];
      int node = b * NPG + q0 + row;
      ab[(size_t)node * HIDD + h * HD + dt * 16 + lr] = f2bf(v);
    }
  }
}

// ---------------- launch ----------------

extern "C" void kernel_launch(void* const* d_in, const int* in_sizes, int n_in,
                              void* d_out, int out_size, void* d_ws, size_t ws_size,
                              hipStream_t stream) {
  const float* x  = (const float*)d_in[0];
  const int*   ei = (const int*)d_in[2];
  const float* ea = (const float*)d_in[3];
  const float* Wq = (const float*)d_in[4];  const float* bq = (const float*)d_in[5];
  const float* Wk = (const float*)d_in[6];  const float* bk = (const float*)d_in[7];
  const float* Wv = (const float*)d_in[8];  const float* bv = (const float*)d_in[9];
  const float* Wo = (const float*)d_in[10]; const float* bo = (const float*)d_in[11];
  const float* We = (const float*)d_in[12]; const float* be = (const float*)d_in[13];

  char* ws = (char*)d_ws;
  const size_t MB = 1 << 20;
  u16*  xb  = (u16*)(ws);             // 16 MiB (aliased as ab after QKV GEMM)
  u16*  wt  = (u16*)(ws + 16*MB);     // 2 MiB
  u16*  qbp = (u16*)(ws + 18*MB);     // 16 MiB
  u16*  kbp = (u16*)(ws + 34*MB);     // 16 MiB
  u16*  vtg = (u16*)(ws + 50*MB);     // 16 MiB  V^T tiled/permuted
  uint32_t* packed = (uint32_t*)(ws + 66*MB);    // 8 MiB
  int*  counts  = (int*)(ws + 74*MB);            // 64 KiB
  int*  cursor  = (int*)(ws + 74*MB + 65536);    // 64 KiB
  int*  rowstart= (int*)(ws + 74*MB + 2*65536);  // 128 KiB region
  u16*  ab = xb;

  (void)hipMemsetAsync(counts, 0, 2 * 65536, stream);

  k_cast_x<<<dim3(NNODE * HIDD / (256 * 8)), 256, 0, stream>>>(x, xb);
  k_transw<<<dim3(16, 16, 4), dim3(32, 8, 1), 0, stream>>>(Wq, Wk, Wv, Wo, wt);
  k_count<<<dim3(NE / 256), 256, 0, stream>>>(ei, counts);
  k_scan<<<1, 1024, 0, stream>>>(counts, rowstart);
  k_fill<<<dim3(NE / 256), 256, 0, stream>>>(ei, ea, We, be, rowstart, cursor, packed);

  k_gemm_qkv<<<dim3(HIDD / 128, NNODE / 128, 3), 256, 0, stream>>>(
      xb, wt, bq, bk, bv, qbp, kbp, vtg);

  k_attn<<<dim3(2048), 256, 0, stream>>>(qbp, kbp, vtg, packed, rowstart, ab);

  k_gemm_out<<<dim3(HIDD / 128, NNODE / 128, 1), 256, 0, stream>>>(
      ab, wt + (size_t)3 * HIDD * HIDD, bo, (float*)d_out);
}